// Round 1
// baseline (796.362 us; speedup 1.0000x reference)
//
#include <hip/hip_runtime.h>
#include <cstdint>

#define B_ 128
#define T_ 1024
#define D_ 256
#define U_ 48

// ---------------------------------------------------------------------------
// K1: logits[row][u] = sum_d x[row][d] * kernel[d][u] + bias[u]
// rows = B*T = 131072. One thread per row; kernel matrix staged in LDS and
// read at wave-uniform addresses (LDS broadcast, conflict-free).
// ---------------------------------------------------------------------------
__global__ __launch_bounds__(256) void k_logits(const float* __restrict__ x,
                                                const float* __restrict__ kern,
                                                const float* __restrict__ bias,
                                                float* __restrict__ logits) {
    __shared__ float K[D_ * U_];   // 48 KB
    __shared__ float bsh[U_];
    const int tid = threadIdx.x;
    for (int i = tid; i < D_ * U_; i += 256) K[i] = kern[i];
    if (tid < U_) bsh[tid] = bias[tid];
    __syncthreads();

    const long row = (long)blockIdx.x * 256 + tid;       // 0..131071, exact
    const float4* xr = (const float4*)(x + row * D_);

    float acc[U_];
#pragma unroll
    for (int u = 0; u < U_; ++u) acc[u] = 0.0f;

    float4 xv = xr[0];
#pragma unroll 1
    for (int d4 = 0; d4 < D_ / 4; ++d4) {
        float4 xnext;
        if (d4 + 1 < D_ / 4) xnext = xr[d4 + 1];
        const float xc[4] = {xv.x, xv.y, xv.z, xv.w};
#pragma unroll
        for (int c = 0; c < 4; ++c) {
            const float4* kp = (const float4*)&K[(d4 * 4 + c) * U_];
            const float xs = xc[c];
#pragma unroll
            for (int u4 = 0; u4 < U_ / 4; ++u4) {
                float4 kv = kp[u4];
                acc[u4 * 4 + 0] += xs * kv.x;
                acc[u4 * 4 + 1] += xs * kv.y;
                acc[u4 * 4 + 2] += xs * kv.z;
                acc[u4 * 4 + 3] += xs * kv.w;
            }
        }
        xv = xnext;
    }

    float4* o4 = (float4*)(logits + row * U_);
#pragma unroll
    for (int i = 0; i < U_ / 4; ++i) {
        float4 v;
        v.x = acc[i * 4 + 0] + bsh[i * 4 + 0];
        v.y = acc[i * 4 + 1] + bsh[i * 4 + 1];
        v.z = acc[i * 4 + 2] + bsh[i * 4 + 2];
        v.w = acc[i * 4 + 3] + bsh[i * 4 + 3];
        o4[i] = v;
    }
}

// ---------------------------------------------------------------------------
// K2: Viterbi forward, max-only (no argmax tracking). One wave per batch.
// lane u holds state[u]; state[v] broadcast via v_readlane; trans column u
// register-resident. delta_t overwrites logits in place (row t read before
// written; row 0 stays = init state).
// ---------------------------------------------------------------------------
__global__ __launch_bounds__(64) void k_forward(const float* __restrict__ trans,
                                                float* __restrict__ delta) {
    const int lane = threadIdx.x;
    const int b = blockIdx.x;
    const int u = (lane < U_) ? lane : (U_ - 1);

    float tc[U_];
#pragma unroll
    for (int v = 0; v < U_; ++v) tc[v] = trans[v * U_ + u];  // column u

    float* base = delta + (long)b * T_ * U_;
    float state = base[u];            // delta_0 = logits row 0
    float nextlogit = base[U_ + u];   // row 1 prefetch

#pragma unroll 1
    for (int t = 1; t < T_; ++t) {
        const float logit = nextlogit;
        const int tn = (t + 1 < T_) ? (t + 1) : (T_ - 1);
        nextlogit = base[tn * U_ + u];                 // prefetch next row

        const int sb = __float_as_int(state);
        float m0 = -3.0e38f, m1 = -3.0e38f, m2 = -3.0e38f, m3 = -3.0e38f;
#pragma unroll
        for (int v = 0; v < U_; v += 8) {
            float c0 = __int_as_float(__builtin_amdgcn_readlane(sb, v + 0)) + tc[v + 0];
            float c1 = __int_as_float(__builtin_amdgcn_readlane(sb, v + 1)) + tc[v + 1];
            float c2 = __int_as_float(__builtin_amdgcn_readlane(sb, v + 2)) + tc[v + 2];
            float c3 = __int_as_float(__builtin_amdgcn_readlane(sb, v + 3)) + tc[v + 3];
            float c4 = __int_as_float(__builtin_amdgcn_readlane(sb, v + 4)) + tc[v + 4];
            float c5 = __int_as_float(__builtin_amdgcn_readlane(sb, v + 5)) + tc[v + 5];
            float c6 = __int_as_float(__builtin_amdgcn_readlane(sb, v + 6)) + tc[v + 6];
            float c7 = __int_as_float(__builtin_amdgcn_readlane(sb, v + 7)) + tc[v + 7];
            m0 = fmaxf(m0, fmaxf(c0, c1));   // -> v_max3
            m1 = fmaxf(m1, fmaxf(c2, c3));
            m2 = fmaxf(m2, fmaxf(c4, c5));
            m3 = fmaxf(m3, fmaxf(c6, c7));
        }
        const float m = fmaxf(fmaxf(m0, m1), fmaxf(m2, m3));
        state = logit + m;                              // exact ref op order
        if (lane < U_) base[t * U_ + u] = state;        // store delta_t
    }
}

// ---------------------------------------------------------------------------
// K3: backpointers recomputed in parallel over all (b,t):
//   bp[b][t][u] = argmax_v(delta[b][t-1][v] + trans[v][u]),
// strict-> ascending scan == numpy first-index tie-break. Candidates are
// bit-identical to K2's, so argmax is consistent with the stored maxes.
// ---------------------------------------------------------------------------
__global__ __launch_bounds__(64) void k_bp(const float* __restrict__ trans,
                                           const float* __restrict__ delta,
                                           unsigned char* __restrict__ bp) {
    const int lane = threadIdx.x;
    const int u = (lane < U_) ? lane : (U_ - 1);

    float tc[U_];
#pragma unroll
    for (int v = 0; v < U_; ++v) tc[v] = trans[v * U_ + u];

    const int NROW = B_ * (T_ - 1);   // 130944
    const int stride = gridDim.x;

    int row = blockIdx.x;
    // prefetch first row
    float dnext = 0.0f;
    if (row < NROW) {
        int b = row / (T_ - 1);
        int t = row - b * (T_ - 1) + 1;
        dnext = delta[((long)b * T_ + (t - 1)) * U_ + u];
    }
#pragma unroll 1
    for (; row < NROW; row += stride) {
        const float dv = dnext;
        const int rn = row + stride;
        if (rn < NROW) {
            int bn = rn / (T_ - 1);
            int tn = rn - bn * (T_ - 1) + 1;
            dnext = delta[((long)bn * T_ + (tn - 1)) * U_ + u];
        }
        const int db = __float_as_int(dv);
        float best = -3.4e38f;
        int bi = 0;
#pragma unroll
        for (int v = 0; v < U_; ++v) {
            float c = __int_as_float(__builtin_amdgcn_readlane(db, v)) + tc[v];
            if (c > best) { best = c; bi = v; }   // strict >: first max wins
        }
        if (lane < U_) bp[(long)row * U_ + u] = (unsigned char)bi;
    }
}

// ---------------------------------------------------------------------------
// K4: backtrace. One block per batch: stage bp[b] (48 KB) in LDS, argmax of
// final state (lane 0, strict-> ascending = first-index), chase through LDS,
// coalesced tag writeback.
// ---------------------------------------------------------------------------
__global__ __launch_bounds__(64) void k_back(const float* __restrict__ delta,
                                             const unsigned char* __restrict__ bp,
                                             float* __restrict__ out) {
    __shared__ unsigned char bpl[(T_ - 1) * U_];  // 49104 B
    __shared__ float tags[T_];                    // 4 KB
    __shared__ float fin[U_];
    const int lane = threadIdx.x;
    const int b = blockIdx.x;

    const uint32_t* src = (const uint32_t*)(bp + (long)b * (T_ - 1) * U_);
    uint32_t* dst = (uint32_t*)bpl;
    const int NW = (T_ - 1) * U_ / 4;             // 12276
    for (int i = lane; i < NW; i += 64) dst[i] = src[i];
    if (lane < U_) fin[lane] = delta[((long)b * T_ + (T_ - 1)) * U_ + lane];
    __syncthreads();

    if (lane == 0) {
        float best = fin[0];
        int tag = 0;
        for (int uu = 1; uu < U_; ++uu)
            if (fin[uu] > best) { best = fin[uu]; tag = uu; }
        tags[T_ - 1] = (float)tag;
        for (int t = T_ - 1; t >= 1; --t) {
            tag = bpl[(t - 1) * U_ + tag];
            tags[t - 1] = (float)tag;
        }
    }
    __syncthreads();

    float* o = out + (long)b * T_;
    for (int i = lane; i < T_; i += 64) o[i] = tags[i];
}

// ---------------------------------------------------------------------------
extern "C" void kernel_launch(void* const* d_in, const int* in_sizes, int n_in,
                              void* d_out, int out_size, void* d_ws, size_t ws_size,
                              hipStream_t stream) {
    const float* x     = (const float*)d_in[0];   // (B,T,D)
    const float* kern  = (const float*)d_in[1];   // (D,U)
    const float* bias  = (const float*)d_in[2];   // (U,)
    const float* trans = (const float*)d_in[3];   // (U,U)
    float* out = (float*)d_out;                   // (B,T) fp32 tags

    float* logits = (float*)d_ws;                                 // 25.2 MB, becomes delta in place
    unsigned char* bp = (unsigned char*)d_ws + (size_t)B_ * T_ * U_ * 4;  // 6.3 MB

    k_logits <<<(B_ * T_) / 256, 256, 0, stream>>>(x, kern, bias, logits);
    k_forward<<<B_,   64, 0, stream>>>(trans, logits);
    k_bp     <<<2048, 64, 0, stream>>>(trans, logits, bp);
    k_back   <<<B_,   64, 0, stream>>>(logits, bp, out);
}

// Round 2
// 715.124 us; speedup vs baseline: 1.1136x; 1.1136x over previous
//
#include <hip/hip_runtime.h>
#include <cstdint>

#define B_ 128
#define T_ 1024
#define D_ 256
#define U_ 48

// ---------------------------------------------------------------------------
// K1: logits[row][u] = sum_d x[row][d] * kernel[d][u] + bias[u]
// rows = B*T = 131072. One thread per row; kernel matrix staged in LDS and
// read at wave-uniform addresses (LDS broadcast, conflict-free).
// ---------------------------------------------------------------------------
__global__ __launch_bounds__(256) void k_logits(const float* __restrict__ x,
                                                const float* __restrict__ kern,
                                                const float* __restrict__ bias,
                                                float* __restrict__ logits) {
    __shared__ float K[D_ * U_];   // 48 KB
    __shared__ float bsh[U_];
    const int tid = threadIdx.x;
    for (int i = tid; i < D_ * U_; i += 256) K[i] = kern[i];
    if (tid < U_) bsh[tid] = bias[tid];
    __syncthreads();

    const long row = (long)blockIdx.x * 256 + tid;       // 0..131071, exact
    const float4* xr = (const float4*)(x + row * D_);

    float acc[U_];
#pragma unroll
    for (int u = 0; u < U_; ++u) acc[u] = 0.0f;

    float4 xv = xr[0];
#pragma unroll 1
    for (int d4 = 0; d4 < D_ / 4; ++d4) {
        float4 xnext;
        if (d4 + 1 < D_ / 4) xnext = xr[d4 + 1];
        const float xc[4] = {xv.x, xv.y, xv.z, xv.w};
#pragma unroll
        for (int c = 0; c < 4; ++c) {
            const float4* kp = (const float4*)&K[(d4 * 4 + c) * U_];
            const float xs = xc[c];
#pragma unroll
            for (int u4 = 0; u4 < U_ / 4; ++u4) {
                float4 kv = kp[u4];
                acc[u4 * 4 + 0] += xs * kv.x;
                acc[u4 * 4 + 1] += xs * kv.y;
                acc[u4 * 4 + 2] += xs * kv.z;
                acc[u4 * 4 + 3] += xs * kv.w;
            }
        }
        xv = xnext;
    }

    float4* o4 = (float4*)(logits + row * U_);
#pragma unroll
    for (int i = 0; i < U_ / 4; ++i) {
        float4 v;
        v.x = acc[i * 4 + 0] + bsh[i * 4 + 0];
        v.y = acc[i * 4 + 1] + bsh[i * 4 + 1];
        v.z = acc[i * 4 + 2] + bsh[i * 4 + 2];
        v.w = acc[i * 4 + 3] + bsh[i * 4 + 3];
        o4[i] = v;
    }
}

// ---------------------------------------------------------------------------
// K2: Viterbi forward, max-only. One wave per batch. lane u holds state[u];
// state[v] broadcast via v_readlane; trans column u register-resident.
// __launch_bounds__(64,1): min 1 wave/EU -> full 512-VGPR budget so tc[48]
// and the prefetch ring stay in registers (R1's 32-VGPR alloc spilled tc ->
// ~970 stall cycles/step reloading it).
// Prefetch depth 4 on logit rows: >=3 iterations of vmcnt slack vs HBM
// latency (~900 cyc).
// ---------------------------------------------------------------------------
__global__ __launch_bounds__(64, 1) void k_forward(const float* __restrict__ trans,
                                                   float* __restrict__ delta) {
    const int lane = threadIdx.x;
    const int b = blockIdx.x;
    const int u = (lane < U_) ? lane : (U_ - 1);

    float tc[U_];
#pragma unroll
    for (int v = 0; v < U_; ++v) tc[v] = trans[v * U_ + u];  // column u

    float* base = delta + (long)b * T_ * U_;
    float state = base[u];            // delta_0 = logits row 0

    float pf[4];
#pragma unroll
    for (int i = 0; i < 4; ++i) pf[i] = base[(1 + i) * U_ + u];  // rows 1..4

#pragma unroll 1
    for (int tb = 1; tb < T_; tb += 4) {
#pragma unroll
        for (int j = 0; j < 4; ++j) {
            const int t = tb + j;
            if (t < T_) {
                const float logit = pf[j];
                int tp = t + 4;
                if (tp > T_ - 1) tp = T_ - 1;
                pf[j] = base[(long)tp * U_ + u];     // refill ring slot j

                const int sb = __float_as_int(state);
                float m0 = -3.0e38f, m1 = -3.0e38f, m2 = -3.0e38f, m3 = -3.0e38f;
#pragma unroll
                for (int v = 0; v < U_; v += 8) {
                    float c0 = __int_as_float(__builtin_amdgcn_readlane(sb, v + 0)) + tc[v + 0];
                    float c1 = __int_as_float(__builtin_amdgcn_readlane(sb, v + 1)) + tc[v + 1];
                    float c2 = __int_as_float(__builtin_amdgcn_readlane(sb, v + 2)) + tc[v + 2];
                    float c3 = __int_as_float(__builtin_amdgcn_readlane(sb, v + 3)) + tc[v + 3];
                    float c4 = __int_as_float(__builtin_amdgcn_readlane(sb, v + 4)) + tc[v + 4];
                    float c5 = __int_as_float(__builtin_amdgcn_readlane(sb, v + 5)) + tc[v + 5];
                    float c6 = __int_as_float(__builtin_amdgcn_readlane(sb, v + 6)) + tc[v + 6];
                    float c7 = __int_as_float(__builtin_amdgcn_readlane(sb, v + 7)) + tc[v + 7];
                    m0 = fmaxf(m0, fmaxf(c0, c1));   // -> v_max3
                    m1 = fmaxf(m1, fmaxf(c2, c3));
                    m2 = fmaxf(m2, fmaxf(c4, c5));
                    m3 = fmaxf(m3, fmaxf(c6, c7));
                }
                const float m = fmaxf(fmaxf(m0, m1), fmaxf(m2, m3));
                state = logit + m;                       // exact ref op order
                if (lane < U_) base[(long)t * U_ + u] = state;
            }
        }
    }
}

// ---------------------------------------------------------------------------
// K3: backpointers recomputed in parallel over all (b,t):
//   bp[b][t][u] = argmax_v(delta[b][t-1][v] + trans[v][u]),
// strict-> ascending scan == numpy first-index tie-break. Candidates are
// bit-identical to K2's, so argmax is consistent with the stored maxes.
// ---------------------------------------------------------------------------
__global__ __launch_bounds__(64, 1) void k_bp(const float* __restrict__ trans,
                                              const float* __restrict__ delta,
                                              unsigned char* __restrict__ bp) {
    const int lane = threadIdx.x;
    const int u = (lane < U_) ? lane : (U_ - 1);

    float tc[U_];
#pragma unroll
    for (int v = 0; v < U_; ++v) tc[v] = trans[v * U_ + u];

    const int NROW = B_ * (T_ - 1);   // 130944
    const int stride = gridDim.x;

    int row = blockIdx.x;
    // prefetch first row
    float dnext = 0.0f;
    if (row < NROW) {
        int b = row / (T_ - 1);
        int t = row - b * (T_ - 1) + 1;
        dnext = delta[((long)b * T_ + (t - 1)) * U_ + u];
    }
#pragma unroll 1
    for (; row < NROW; row += stride) {
        const float dv = dnext;
        const int rn = row + stride;
        if (rn < NROW) {
            int bn = rn / (T_ - 1);
            int tn = rn - bn * (T_ - 1) + 1;
            dnext = delta[((long)bn * T_ + (tn - 1)) * U_ + u];
        }
        const int db = __float_as_int(dv);
        float best = -3.4e38f;
        int bi = 0;
#pragma unroll
        for (int v = 0; v < U_; ++v) {
            float c = __int_as_float(__builtin_amdgcn_readlane(db, v)) + tc[v];
            if (c > best) { best = c; bi = v; }   // strict >: first max wins
        }
        if (lane < U_) bp[(long)row * U_ + u] = (unsigned char)bi;
    }
}

// ---------------------------------------------------------------------------
// K4: backtrace. One block per batch: stage bp[b] (48 KB) in LDS, argmax of
// final state (lane 0, strict-> ascending = first-index), chase through LDS,
// coalesced tag writeback.
// ---------------------------------------------------------------------------
__global__ __launch_bounds__(64) void k_back(const float* __restrict__ delta,
                                             const unsigned char* __restrict__ bp,
                                             float* __restrict__ out) {
    __shared__ unsigned char bpl[(T_ - 1) * U_];  // 49104 B
    __shared__ float tags[T_];                    // 4 KB
    __shared__ float fin[U_];
    const int lane = threadIdx.x;
    const int b = blockIdx.x;

    const uint32_t* src = (const uint32_t*)(bp + (long)b * (T_ - 1) * U_);
    uint32_t* dst = (uint32_t*)bpl;
    const int NW = (T_ - 1) * U_ / 4;             // 12276
    for (int i = lane; i < NW; i += 64) dst[i] = src[i];
    if (lane < U_) fin[lane] = delta[((long)b * T_ + (T_ - 1)) * U_ + lane];
    __syncthreads();

    if (lane == 0) {
        float best = fin[0];
        int tag = 0;
        for (int uu = 1; uu < U_; ++uu)
            if (fin[uu] > best) { best = fin[uu]; tag = uu; }
        tags[T_ - 1] = (float)tag;
        for (int t = T_ - 1; t >= 1; --t) {
            tag = bpl[(t - 1) * U_ + tag];
            tags[t - 1] = (float)tag;
        }
    }
    __syncthreads();

    float* o = out + (long)b * T_;
    for (int i = lane; i < T_; i += 64) o[i] = tags[i];
}

// ---------------------------------------------------------------------------
extern "C" void kernel_launch(void* const* d_in, const int* in_sizes, int n_in,
                              void* d_out, int out_size, void* d_ws, size_t ws_size,
                              hipStream_t stream) {
    const float* x     = (const float*)d_in[0];   // (B,T,D)
    const float* kern  = (const float*)d_in[1];   // (D,U)
    const float* bias  = (const float*)d_in[2];   // (U,)
    const float* trans = (const float*)d_in[3];   // (U,U)
    float* out = (float*)d_out;                   // (B,T) fp32 tags

    float* logits = (float*)d_ws;                                 // 25.2 MB, becomes delta in place
    unsigned char* bp = (unsigned char*)d_ws + (size_t)B_ * T_ * U_ * 4;  // 6.3 MB

    k_logits <<<(B_ * T_) / 256, 256, 0, stream>>>(x, kern, bias, logits);
    k_forward<<<B_,   64, 0, stream>>>(trans, logits);
    k_bp     <<<2048, 64, 0, stream>>>(trans, logits, bp);
    k_back   <<<B_,   64, 0, stream>>>(logits, bp, out);
}